// Round 4
// baseline (435.656 us; speedup 1.0000x reference)
//
#include <hip/hip_runtime.h>

#define B_ 2
#define T_ 2048
#define D_ 2048
#define N_ 16
#define H_ 128
constexpr int WIN = 1024;

typedef __attribute__((ext_vector_type(8))) short s16x8;
typedef __attribute__((ext_vector_type(4))) float f32x4;
typedef __attribute__((ext_vector_type(4))) unsigned short u16x4;

typedef const __attribute__((address_space(1))) void cglobal_void;
typedef __attribute__((address_space(3))) void lds_void;

__device__ __forceinline__ unsigned short f2b(float f) {
  union { float f; unsigned u; } v; v.f = f;
  unsigned r = v.u + 0x7FFFu + ((v.u >> 16) & 1u);
  return (unsigned short)(r >> 16);
}
__device__ __forceinline__ float b2f(unsigned short u) {
  union { unsigned u; float f; } v; v.u = ((unsigned)u) << 16;
  return v.f;
}

// ---------------------------------------------------------------------------
// Dtype detector (fp32 vs bf16 inputs): fp32 mantissa halves look like big
// exponents ~40% of the time; bf16 activations never.
// ---------------------------------------------------------------------------
__global__ __launch_bounds__(256) void detect_kernel(
    const unsigned short* __restrict__ x, int* __restrict__ flag) {
  __shared__ int cnt[256];
  const int tid = threadIdx.x;
  int c = 0;
  for (int i = tid; i < 4096; i += 256) {
    const unsigned short u = x[2 * i];
    const int e = (u >> 7) & 0xFF;
    if (e >= 154) ++c;
  }
  cnt[tid] = c;
  __syncthreads();
  for (int s = 128; s > 0; s >>= 1) {
    if (tid < s) cnt[tid] += cnt[tid + s];
    __syncthreads();
  }
  if (tid == 0) *flag = cnt[0];
}

// x -> canonical bf16, 4 elems/thread
__global__ __launch_bounds__(256) void convert_x_kernel(
    const void* __restrict__ src, unsigned short* __restrict__ dst,
    const int* __restrict__ flag, int n4) {
  const int i = blockIdx.x * 256 + threadIdx.x;
  if (i >= n4) return;
  const bool isf = (*flag > 64);
  u16x4 o;
  if (isf) {
    const float4 f = ((const float4*)src)[i];
    o[0] = f2b(f.x); o[1] = f2b(f.y); o[2] = f2b(f.z); o[3] = f2b(f.w);
  } else {
    o = ((const u16x4*)src)[i];
  }
  *(u16x4*)(dst + 4 * (size_t)i) = o;
}

// ---------------------------------------------------------------------------
// Batched tiled transpose, dtype-adaptive input, bf16 out.
// ---------------------------------------------------------------------------
__global__ __launch_bounds__(256) void transpose_kernel(
    const void* __restrict__ src, unsigned short* __restrict__ dst,
    int R, int C, const int* __restrict__ flag) {
  __shared__ unsigned short tile[32][33];
  const bool isf = (*flag > 64);
  const int c0 = blockIdx.x * 32, r0 = blockIdx.y * 32;
  const size_t base = (size_t)blockIdx.z * R * C;
  const int tx = threadIdx.x, ty = threadIdx.y;
#pragma unroll
  for (int j = 0; j < 32; j += 8) {
    const size_t idx = base + (size_t)(r0 + ty + j) * C + c0 + tx;
    tile[ty + j][tx] = isf ? f2b(((const float*)src)[idx])
                           : ((const unsigned short*)src)[idx];
  }
  __syncthreads();
#pragma unroll
  for (int j = 0; j < 32; j += 8)
    dst[base + (size_t)(c0 + ty + j) * R + r0 + tx] = tile[tx][ty + j];
}

// bf16-only batched transpose (V [t][h] -> [h][t] per (b,n))
__global__ __launch_bounds__(256) void transpose_bf16_kernel(
    const unsigned short* __restrict__ src, unsigned short* __restrict__ dst,
    int R, int C) {
  __shared__ unsigned short tile[32][33];
  const int c0 = blockIdx.x * 32, r0 = blockIdx.y * 32;
  const size_t base = (size_t)blockIdx.z * R * C;
  const int tx = threadIdx.x, ty = threadIdx.y;
#pragma unroll
  for (int j = 0; j < 32; j += 8)
    tile[ty + j][tx] = src[base + (size_t)(r0 + ty + j) * C + c0 + tx];
  __syncthreads();
#pragma unroll
  for (int j = 0; j < 32; j += 8)
    dst[base + (size_t)(c0 + ty + j) * R + r0 + tx] = tile[tx][ty + j];
}

// ---------------------------------------------------------------------------
// 256x256-tile bf16 GEMM (QKV projection), K=2048, BK=64, 8 waves (2M x 4N),
// 8-phase schedule, counted vmcnt(4), setprio.
// R4 changes vs R1 (same staging cadence, same VM4 points, same arithmetic):
//  - NO explicit lgkmcnt(0) drain / sched_barrier before MFMA: ds_reads are
//    plain loads; compiler emits fine-grained lgkmcnt so early MFMAs overlap
//    late read returns (m97 r109). Reads stay fenced after their guaranteeing
//    vmcnt by the asm-volatile memory clobber on VM4.
//  - balanced ds_reads 8/4 per phase via mb-split MFMA: ph even reads
//    af[0..3]+bf[0..3] (8xb128) and computes mb0-3 x nb0-3; ph odd reads
//    af[4..7] (4xb128), reuses bf in regs, computes mb4-7.
// ---------------------------------------------------------------------------
__global__ __launch_bounds__(512, 2) void gemm256_kernel(
    const unsigned short* __restrict__ A,
    const unsigned short* __restrict__ Bt,
    void* __restrict__ outp,
    int mode, const int* __restrict__ flag) {
  constexpr int K = D_;
  __shared__ unsigned short As[2][16384];
  __shared__ unsigned short Bs[2][16384];
  const int tid = threadIdx.x;
  const int lane = tid & 63;
  const int lr = lane & 15, lq = lane >> 4;
  const int wave = tid >> 6;
  const int wm = (wave >> 2) * 128, wn = (wave & 3) * 64;
  const size_t m0 = (size_t)blockIdx.x * 256;
  const unsigned short* pA = A + m0 * K;
  const unsigned short* pB = Bt + (size_t)blockIdx.y * 256 * K;

  // flag read pinned BEFORE prologue staging + drained, so the hand-counted
  // vmcnt(4)s below only ever count our global_load_lds ops.
  const int fv = *flag;
  asm volatile("s_waitcnt vmcnt(0)" ::: "memory");

  // staging geometry: per half-tile, slot16B = j*512+tid (j=0,1);
  // row = j*128+(tid>>2), phys chunk = tid&3, global chunk = phys ^ ((row>>1)&3)
  const int cgs = (tid & 3) ^ ((tid >> 3) & 3);
  const size_t gbase = (size_t)(tid >> 2) * K + (size_t)(cgs * 8);

  // fragment-read bases (ushort offsets): row stride 32, chunk = lq ^ ((row>>1)&3)
  const int swz = (lr >> 1) & 3;
  const int aoff = (wm + lr) * 32 + ((lq ^ swz) << 3);
  const int boff = (wn + lr) * 32 + ((lq ^ swz) << 3);

  f32x4 acc[8][4] = {};
  s16x8 af[4], bf[4];

#define STAGE(mat, ptr, ibuf, kk, h)                                          \
  {                                                                           \
    _Pragma("unroll")                                                         \
    for (int j = 0; j < 2; ++j)                                               \
      __builtin_amdgcn_global_load_lds(                                       \
          (cglobal_void*)((ptr) + gbase + (size_t)j * 128 * K + (kk) + (h) * 32), \
          (lds_void*)(&mat[ibuf][(h) * 8192 + (j * 512 + tid) * 8]), 16, 0, 0); \
  }

  // mh = 0: af[0..3] = rows wm+{0..3}*16 ; mh = 1: rows wm+{4..7}*16
#define LOAD_AF(kq, mh)                                                       \
  {                                                                           \
    _Pragma("unroll")                                                         \
    for (int i = 0; i < 4; ++i)                                               \
      af[i] = *(const s16x8*)(&As[ib][(kq) * 8192 + aoff + ((mh) * 4 + i) * 512]); \
  }

#define LOAD_BF(kq)                                                           \
  {                                                                           \
    _Pragma("unroll")                                                         \
    for (int nb = 0; nb < 4; ++nb)                                            \
      bf[nb] = *(const s16x8*)(&Bs[ib][(kq) * 8192 + boff + nb * 512]);       \
  }

#define MFMA16(mh)                                                            \
  __builtin_amdgcn_s_setprio(1);                                              \
  {                                                                           \
    _Pragma("unroll")                                                         \
    for (int mb = 0; mb < 4; ++mb) {                                          \
      _Pragma("unroll")                                                       \
      for (int nb = 0; nb < 4; ++nb)                                          \
        acc[(mh) * 4 + mb][nb] = __builtin_amdgcn_mfma_f32_16x16x32_bf16(     \
            af[mb], bf[nb], acc[(mh) * 4 + mb][nb], 0, 0, 0);                 \
    }                                                                         \
  }                                                                           \
  __builtin_amdgcn_s_setprio(0);

#define BAR() __builtin_amdgcn_s_barrier();
#define VM4() asm volatile("s_waitcnt vmcnt(4)" ::: "memory");

  // prologue: stage K-tile 0 into buf 0 (order: A0h0, B0h0, A0h1, B0h1)
  STAGE(As, pA, 0, 0, 0);
  STAGE(Bs, pB, 0, 0, 0);
  STAGE(As, pA, 0, 0, 1);
  STAGE(Bs, pB, 0, 0, 1);
  VM4();  // A0h0,B0h0 landed; A0h1,B0h1 (4 loads) stay in flight
  BAR();

  for (int t = 0; t < K / 64; ++t) {
    const int ib = t & 1;
    const int kn = (t + 1) * 64;  // next K-tile (t=31 reads mapped scratch)
    // phase 0: kslice 0, mb 0-3 (8 ds_reads)
    LOAD_AF(0, 0); LOAD_BF(0);
    STAGE(As, pA, ib ^ 1, kn, 0);
    BAR(); MFMA16(0); BAR();
    // phase 1: kslice 0, mb 4-7 (4 ds_reads, bf reused)
    LOAD_AF(0, 1);
    STAGE(Bs, pB, ib ^ 1, kn, 0);
    VM4();  // lands A-h1,B-h1 of K-tile t (read in phase 2)
    BAR(); MFMA16(1); BAR();
    // phase 2: kslice 1, mb 0-3
    LOAD_AF(1, 0); LOAD_BF(1);
    STAGE(As, pA, ib ^ 1, kn, 1);
    BAR(); MFMA16(0); BAR();
    // phase 3: kslice 1, mb 4-7
    LOAD_AF(1, 1);
    STAGE(Bs, pB, ib ^ 1, kn, 1);
    VM4();  // lands A-h0,B-h0 of K-tile t+1 (read in next phase 0)
    BAR(); MFMA16(1); BAR();
  }

  const int n0 = blockIdx.y << 8;
  if (mode == 0) {
    const bool isf = (fv > 64);
#pragma unroll
    for (int mb = 0; mb < 8; ++mb) {
#pragma unroll
      for (int i = 0; i < 4; ++i) {
        const size_t r = m0 + wm + mb * 16 + lq * 4 + i;
#pragma unroll
        for (int nb = 0; nb < 4; ++nb) {
          const size_t c = (size_t)(n0 + wn + nb * 16 + lr);
          if (isf) ((float*)outp)[r * D_ + c] = acc[mb][nb][i];
          else ((unsigned short*)outp)[r * D_ + c] = f2b(acc[mb][nb][i]);
        }
      }
    }
  } else {
    unsigned short* op = (unsigned short*)outp;
    const size_t SB = (size_t)B_ * N_ * T_ * H_;
#pragma unroll
    for (int mb = 0; mb < 8; ++mb) {
#pragma unroll
      for (int i = 0; i < 4; ++i) {
        const size_t r = m0 + wm + mb * 16 + lq * 4 + i;
        const int b = (int)(r >> 11);
        const int tt = (int)(r & 2047);
#pragma unroll
        for (int nb = 0; nb < 4; ++nb) {
          const int g = n0 + wn + nb * 16 + lr;
          const int s = g >> 11, n = (g >> 7) & 15, h = g & 127;
          op[(size_t)s * SB + (size_t)(b * N_ + n) * T_ * H_ +
             (size_t)tt * H_ + h] = f2b(acc[mb][nb][i]);
        }
      }
    }
  }
#undef STAGE
#undef LOAD_AF
#undef LOAD_BF
#undef MFMA16
#undef BAR
#undef VM4
}

// ---------------------------------------------------------------------------
// 256x128-tile bf16 GEMM (out-projection): 256 blocks, all co-resident.
// Triple-buffered LDS, counted vmcnt(6), setprio, XCD swizzle. R4: removed
// the lgkmcnt(0) drain / sched_barrier (compiler-managed fine-grained waits).
// ---------------------------------------------------------------------------
__global__ __launch_bounds__(512, 2) void gemm256x128_kernel(
    const unsigned short* __restrict__ A,
    const unsigned short* __restrict__ Bt,
    void* __restrict__ outp,
    int mode, const int* __restrict__ flag) {
  constexpr int K = D_;
  __shared__ unsigned short As[3 * 16384];
  __shared__ unsigned short Bs[3 * 8192];
  const int tid = threadIdx.x;
  const int lane = tid & 63;
  const int lr = lane & 15, lq = lane >> 4;
  const int wave = tid >> 6;
  const int wm = (wave >> 1) * 64, wn = (wave & 1) * 64;

  // T1: bijective XCD-chunked swizzle (gridDim.x == 16).
  const int lin = blockIdx.y * 16 + blockIdx.x;
  const int nblk = (int)(gridDim.x * gridDim.y);  // 256, %8==0
  const int wg = (lin & 7) * (nblk >> 3) + (lin >> 3);
  const int bx = wg & 15;
  const int by = wg >> 4;

  const size_t m0 = (size_t)bx * 256;
  const unsigned short* pA = A + m0 * K;
  const unsigned short* pB = Bt + (size_t)by * 128 * K;

  const int fv = *flag;
  asm volatile("s_waitcnt vmcnt(0)" ::: "memory");

  const int cgs = (tid & 3) ^ ((tid >> 3) & 3);
  const size_t gbase = (size_t)(tid >> 2) * K + (size_t)(cgs * 8);

  const int swz = (lr >> 1) & 3;
  const int aoff = (wm + lr) * 32 + ((lq ^ swz) << 3);
  const int boff = (wn + lr) * 32 + ((lq ^ swz) << 3);

  f32x4 acc[4][4] = {};
  s16x8 af[4], bf[4];

#define STAGE_A(bufp, kk, h)                                                  \
  {                                                                           \
    _Pragma("unroll")                                                         \
    for (int j = 0; j < 2; ++j)                                               \
      __builtin_amdgcn_global_load_lds(                                       \
          (cglobal_void*)(pA + gbase + (size_t)j * 128 * K + (kk) + (h) * 32),\
          (lds_void*)((bufp) + (h) * 8192 + (j * 512 + tid) * 8), 16, 0, 0);  \
  }
#define STAGE_B(bufp, kk, h)                                                  \
  __builtin_amdgcn_global_load_lds(                                           \
      (cglobal_void*)(pB + gbase + (kk) + (h) * 32),                          \
      (lds_void*)((bufp) + (h) * 4096 + tid * 8), 16, 0, 0);

#define LOAD_F(h)                                                             \
  {                                                                           \
    _Pragma("unroll")                                                         \
    for (int i = 0; i < 4; ++i) {                                             \
      af[i] = *(const s16x8*)(Ab + (h) * 8192 + aoff + i * 512);              \
      bf[i] = *(const s16x8*)(Bb + (h) * 4096 + boff + i * 512);              \
    }                                                                         \
  }

#define MFMA16()                                                              \
  __builtin_amdgcn_s_setprio(1);                                              \
  {                                                                           \
    _Pragma("unroll")                                                         \
    for (int mb = 0; mb < 4; ++mb) {                                          \
      _Pragma("unroll")                                                       \
      for (int nb = 0; nb < 4; ++nb)                                          \
        acc[mb][nb] = __builtin_amdgcn_mfma_f32_16x16x32_bf16(                \
            af[mb], bf[nb], acc[mb][nb], 0, 0, 0);                            \
    }                                                                         \
  }                                                                           \
  __builtin_amdgcn_s_setprio(0);

#define BAR() __builtin_amdgcn_s_barrier();
#define VM6() asm volatile("s_waitcnt vmcnt(6)" ::: "memory");

  STAGE_A(As, 0, 0); STAGE_A(As, 0, 1); STAGE_B(Bs, 0, 0); STAGE_B(Bs, 0, 1);
  STAGE_A(As + 16384, 64, 0); STAGE_A(As + 16384, 64, 1);
  STAGE_B(Bs + 8192, 64, 0);  STAGE_B(Bs + 8192, 64, 1);
  VM6();
  BAR();

  int bt = 0, bp = 2;
  for (int t = 0; t < K / 64; ++t) {
    const unsigned short* Ab = As + bt * 16384;
    const unsigned short* Bb = Bs + bt * 8192;
    unsigned short* Ap = As + bp * 16384;
    unsigned short* Bp = Bs + bp * 8192;
    const int kn = (t + 2) * 64;  // prefetch K-tile t+2 (tail spills <1KB)
    LOAD_F(0);
    STAGE_A(Ap, kn, 0); STAGE_B(Bp, kn, 0);
    BAR(); MFMA16(); BAR();
    LOAD_F(1);
    STAGE_A(Ap, kn, 1); STAGE_B(Bp, kn, 1);
    VM6();
    BAR(); MFMA16(); BAR();
    bt = (bt == 2) ? 0 : bt + 1;
    bp = (bp == 2) ? 0 : bp + 1;
  }

  const int n0 = by << 7;
  if (mode == 0) {
    const bool isf = (fv > 64);
#pragma unroll
    for (int mb = 0; mb < 4; ++mb) {
#pragma unroll
      for (int i = 0; i < 4; ++i) {
        const size_t r = m0 + wm + mb * 16 + lq * 4 + i;
#pragma unroll
        for (int nb = 0; nb < 4; ++nb) {
          const size_t c = (size_t)(n0 + wn + nb * 16 + lr);
          if (isf) ((float*)outp)[r * D_ + c] = acc[mb][nb][i];
          else ((unsigned short*)outp)[r * D_ + c] = f2b(acc[mb][nb][i]);
        }
      }
    }
  } else {
    unsigned short* op = (unsigned short*)outp;
    const size_t SB = (size_t)B_ * N_ * T_ * H_;
#pragma unroll
    for (int mb = 0; mb < 4; ++mb) {
#pragma unroll
      for (int i = 0; i < 4; ++i) {
        const size_t r = m0 + wm + mb * 16 + lq * 4 + i;
        const int b = (int)(r >> 11);
        const int tt = (int)(r & 2047);
#pragma unroll
        for (int nb = 0; nb < 4; ++nb) {
          const int g = n0 + wn + nb * 16 + lr;
          const int s = g >> 11, n = (g >> 7) & 15, h = g & 127;
          op[(size_t)s * SB + (size_t)(b * N_ + n) * T_ * H_ +
             (size_t)tt * H_ + h] = f2b(acc[mb][nb][i]);
        }
      }
    }
  }
#undef STAGE_A
#undef STAGE_B
#undef LOAD_F
#undef MFMA16
#undef BAR
#undef VM6
}

// ---------------------------------------------------------------------------
// RoPE in place on q,k rows. One wave per 128-elem row; q scaled by H^-0.5.
// ---------------------------------------------------------------------------
__global__ __launch_bounds__(256) void rope_kernel(unsigned short* __restrict__ qk) {
  const int tid = threadIdx.x;
  const int lane = tid & 63;
  const size_t row = (size_t)blockIdx.x * 4 + (tid >> 6);
  const int t = (int)(row & (T_ - 1));
  const int s = (int)(row >> 16);
  unsigned short* p = qk + row * H_;
  float x1 = b2f(p[lane]), x2 = b2f(p[lane + 64]);
  // timescale^-1 = 10000^(-lane/64) = exp2(-lane*log2(10000)/64)
  const float inv_ts = exp2f(-0.20762050f * (float)lane);
  float sv, cv;
  __sincosf((float)t * inv_ts, &sv, &cv);
  float o1 = x1 * cv - x2 * sv;
  float o2 = x2 * cv + x1 * sv;
  if (s == 0) { o1 *= 0.08838834764831845f; o2 *= 0.08838834764831845f; }
  p[lane] = f2b(o1);
  p[lane + 64] = f2b(o2);
}

// ---------------------------------------------------------------------------
// Flash attention, double-buffered K/V prefetch (T3/T4/T14 applied).
//   Ks[2][64 key][128 h] : phys chunk16 = logical ^ (key&15)
//   Vt[2][128 h][64 key] : phys chunk8  = logical ^ (h&7)
//   Psm[wave][16x64]     : per-wave PRIVATE -> P write/read needs no barrier
// Per iter: issue 8 global_load_lds for tile i+1 (unconditional; tail strays
// <=16KB into allocated ws so vmcnt counts stay uniform), s_waitcnt vmcnt(8)
// (tile i complete, tile i+1 in flight), raw s_barrier, QK^T, softmax, P
// (wave-local), PV, raw s_barrier. LDS 72KB -> 2 blocks/CU.
// p = exp2(-2*C_T*rcp(u+1) + BIAS), u = exp2(a*C_IN): same softmax weights
// (constant absorbed by l).
// ---------------------------------------------------------------------------
__global__ __launch_bounds__(256, 2) void attn_kernel(
    const unsigned short* __restrict__ qkv,
    const unsigned short* __restrict__ vt,
    unsigned short* __restrict__ enc) {
  const int tid = threadIdx.x, lane = tid & 63, wave = tid >> 6;
  const int lr = lane & 15, lq = lane >> 4;
  const int bn = blockIdx.x;
  const int b = bn >> 4, n = bn & 15;
  const int t0 = blockIdx.y * 64;
  const size_t SB = (size_t)B_ * N_ * T_ * H_;
  const unsigned short* qp = qkv + (size_t)bn * T_ * H_;
  const unsigned short* kp = qp + SB;
  const unsigned short* vp = vt + (size_t)bn * T_ * H_;  // [h][t]

  __shared__ unsigned short Ks[2][64 * 128];
  __shared__ unsigned short Vt[2][128 * 64];
  __shared__ unsigned short Psm[4][16 * 64];
  unsigned short* Ps = Psm[wave];  // per-wave private: no barrier needed

  // staging offsets (lane-invariant across j except row):
  const int cgK = (tid & 15) ^ ((tid >> 4) & 15);   // 16 chunks/row
  const int cgV = (tid & 7) ^ ((tid >> 3) & 7);     // 8 chunks/row
  size_t goffK[4], goffV[4];
#pragma unroll
  for (int j = 0; j < 4; ++j) {
    goffK[j] = (size_t)(j * 16 + (tid >> 4)) * H_ + cgK * 8;
    goffV[j] = (size_t)(j * 32 + (tid >> 3)) * T_ + cgV * 8;
  }

  // Q fragments (A-layout), registers for whole kernel
  s16x8 aq[4];
  {
    const int t = t0 + wave * 16 + lr;
#pragma unroll
    for (int kc = 0; kc < 4; ++kc)
      aq[kc] = *(const s16x8*)(qp + (size_t)t * H_ + kc * 32 + lq * 8);
  }
  // drain Q loads so the hand-counted vmcnt(8) below only counts staging
  asm volatile("s_waitcnt vmcnt(0)" ::: "memory");

#define STAGE_T(ibuf, s0v)                                                    \
  {                                                                           \
    _Pragma("unroll")                                                         \
    for (int j = 0; j < 4; ++j) {                                             \
      __builtin_amdgcn_global_load_lds(                                       \
          (cglobal_void*)(kp + (size_t)(s0v) * H_ + goffK[j]),                \
          (lds_void*)(Ks[ibuf] + (size_t)(j * 256 + tid) * 8), 16, 0, 0);     \
      __builtin_amdgcn_global_load_lds(                                       \
          (cglobal_void*)(vp + goffV[j] + (s0v)),                             \
          (lds_void*)(Vt[ibuf] + (size_t)(j * 256 + tid) * 8), 16, 0, 0);     \
    }                                                                         \
  }

  f32x4 oacc[8] = {};
  float lp[4] = {0.f, 0.f, 0.f, 0.f};

  const int s_lo = (t0 >= WIN - 1) ? ((t0 - (WIN - 1)) & ~63) : 0;
  constexpr float C_IN = 0.05770780f;     // 2*log2(e)/50
  constexpr float M_SCALE = -144.269504f; // -2*50*log2(e)
  constexpr float M_BIAS = 86.56f;        // keeps p in [2^-58, 2^87]

  // prologue: tile s_lo -> buf 0 (8 loads in flight)
  STAGE_T(0, s_lo);

  int cur = 0;
  for (int s0 = s_lo; s0 <= t0 + 63; s0 += 64) {
    // prefetch next tile into the other buffer (safe: all waves passed the
    // previous iteration's end barrier, so reads of that buffer are done;
    // tail iteration strays into adjacent allocated workspace, values unused)
    STAGE_T(cur ^ 1, s0 + 64);
    asm volatile("s_waitcnt vmcnt(8)" ::: "memory");  // tile s0 landed
    __builtin_amdgcn_s_barrier();                     // visible to all waves

    const unsigned short* Kb = Ks[cur];
    const unsigned short* Vb = Vt[cur];

    // QK^T -> p
    float p[4][4];
#pragma unroll
    for (int sb = 0; sb < 4; ++sb) {
      f32x4 a = {};
#pragma unroll
      for (int kc = 0; kc < 4; ++kc) {
        const int co = (((kc << 2) + lq) ^ lr) * 8;
        s16x8 bk = *(const s16x8*)(Kb + (sb * 16 + lr) * 128 + co);
        a = __builtin_amdgcn_mfma_f32_16x16x32_bf16(aq[kc], bk, a, 0, 0, 0);
      }
#pragma unroll
      for (int i = 0; i < 4; ++i) {
        const float u = exp2f(a[i] * C_IN);
        const float r = __builtin_amdgcn_rcpf(u + 1.0f);
        p[sb][i] = exp2f(fmaf(r, M_SCALE, M_BIAS));
      }
    }

    // mask only boundary tiles (wave-uniform branch)
    const bool interior = (s0 + 63 <= t0) && (s0 >= t0 + 63 - (WIN - 1));
    if (!interior) {
#pragma unroll
      for (int sb = 0; sb < 4; ++sb) {
        const int key = s0 + sb * 16 + lr;
#pragma unroll
        for (int i = 0; i < 4; ++i) {
          const int t = t0 + wave * 16 + lq * 4 + i;
          if (key > t || key < t - (WIN - 1)) p[sb][i] = 0.0f;
        }
      }
    }
#pragma unroll
    for (int sb = 0; sb < 4; ++sb)
#pragma unroll
      for (int i = 0; i < 4; ++i) lp[i] += p[sb][i];

    // P -> per-wave private LDS (no barrier: same-wave write->read, lgkmcnt)
#pragma unroll
    for (int sb = 0; sb < 4; ++sb)
#pragma unroll
      for (int i = 0; i < 4; ++i) {
        const int row = lq * 4 + i;
        const int cph = ((sb * 2 + (lr >> 3)) ^ (row & 7));
        Ps[row * 64 + cph * 8 + (lr & 7)] = f2b(p[sb][i]);
      }

    s16x8 ap[2];
#pragma unroll
    for (int kc = 0; kc < 2; ++kc)
      ap[kc] = *(const s16x8*)(Ps + lr * 64 + ((((kc << 2) + lq) ^ (lr & 7)) * 8));

#pragma unroll
    for (int hb = 0; hb < 8; ++hb) {
#pragma unroll
      for (int kc = 0; kc < 2; ++kc) {
        const int co = (((kc << 2) + lq) ^ (lr & 7)) * 8;
        s16x8 bv = *(const s16x8*)(Vb + (hb * 16 + lr) * 64 + co);
        oacc[hb] = __builtin_amdgcn_mfma_f32_16x16x32_bf16(ap[kc], bv, oacc[hb], 0, 0, 0);
      }
    }

    __builtin_amdgcn_s_barrier();  // all reads of buf cur complete
    cur ^= 1;
  }
#undef STAGE_T

  // l: reduce per-lane partials across the 16 lr-lanes
#pragma unroll
  for (int i = 0; i < 4; ++i) {
#pragma unroll
    for (int off = 1; off < 16; off <<= 1)
      lp[i] += __shfl_xor(lp[i], off, 64);
  }

#pragma unroll
  for (int i = 0; i < 4; ++i) {
    const int t = t0 + wave * 16 + lq * 4 + i;
    const float inv = 1.0f / lp[i];
    const size_t rowb = ((size_t)b * T_ + t) * (N_ * H_) + (size_t)n * H_;
#pragma unroll
    for (int hb = 0; hb < 8; ++hb)
      enc[rowb + hb * 16 + lr] = f2b(oacc[hb][i] * inv);
  }
}

// ---------------------------------------------------------------------------
extern "C" void kernel_launch(void* const* d_in, const int* in_sizes, int n_in,
                              void* d_out, int out_size, void* d_ws, size_t ws_size,
                              hipStream_t stream) {
  const void* x     = d_in[0];  // (B,T,D)    fp32 (auto-detected; bf16 hedge)
  const void* w_qkv = d_in[1];  // (3,N,D,H)
  const void* w_out = d_in[2];  // (N,H,D)

  // workspace (88 MB peak, proven safe):
  //   [0,64)          flag
  //   A [64,+16MB)    xc        -> later vt (v transposed, 16MB)
  //   B [+16,+40MB)   wqkvT     -> later enc(16MB) + woutT(8MB)
  //   C [+40,+88MB)   qkv: q(16) k(16) v(16)
  char* wsb = (char*)d_ws;
  int* flag = (int*)wsb;
  const size_t MB = 1048576;
  unsigned short* xc    = (unsigned short*)(wsb + 64);
  unsigned short* wqkvT = (unsigned short*)(wsb + 64 + 16 * MB);
  unsigned short* qkv   = (unsigned short*)(wsb + 64 + 40 * MB);
  unsigned short* vt    = xc;                                        // alias
  unsigned short* enc   = wqkvT;                                     // alias
  unsigned short* woutT = (unsigned short*)(wsb + 64 + 32 * MB);     // alias
  unsigned short* v     = qkv + 2 * (size_t)B_ * N_ * T_ * H_;

  detect_kernel<<<1, 256, 0, stream>>>((const unsigned short*)x, flag);
  convert_x_kernel<<<8192, 256, 0, stream>>>(x, xc, flag, B_ * T_ * D_ / 4);
  transpose_kernel<<<dim3(4, 64, 48), dim3(32, 8), 0, stream>>>(w_qkv, wqkvT, 2048, 128, flag);
  gemm256_kernel<<<dim3(16, 24), 512, 0, stream>>>(xc, wqkvT, qkv, 1, flag);
  rope_kernel<<<32768, 256, 0, stream>>>(qkv);
  transpose_bf16_kernel<<<dim3(4, 64, 32), dim3(32, 8), 0, stream>>>(v, vt, 2048, 128);
  transpose_kernel<<<dim3(64, 64, 1), dim3(32, 8), 0, stream>>>(w_out, woutT, 2048, 2048, flag);
  attn_kernel<<<dim3(32, 32), 256, 0, stream>>>(qkv, vt, enc);
  gemm256x128_kernel<<<dim3(16, 16), 512, 0, stream>>>(enc, woutT, d_out, 0, flag);
}

// Round 5
// 415.493 us; speedup vs baseline: 1.0485x; 1.0485x over previous
//
#include <hip/hip_runtime.h>

#define B_ 2
#define T_ 2048
#define D_ 2048
#define N_ 16
#define H_ 128
constexpr int WIN = 1024;

typedef __attribute__((ext_vector_type(8))) short s16x8;
typedef __attribute__((ext_vector_type(4))) float f32x4;
typedef __attribute__((ext_vector_type(4))) unsigned short u16x4;

typedef const __attribute__((address_space(1))) void cglobal_void;
typedef __attribute__((address_space(3))) void lds_void;

__device__ __forceinline__ unsigned short f2b(float f) {
  union { float f; unsigned u; } v; v.f = f;
  unsigned r = v.u + 0x7FFFu + ((v.u >> 16) & 1u);
  return (unsigned short)(r >> 16);
}
__device__ __forceinline__ float b2f(unsigned short u) {
  union { unsigned u; float f; } v; v.u = ((unsigned)u) << 16;
  return v.f;
}

// ---------------------------------------------------------------------------
// Dtype detector (fp32 vs bf16 inputs): fp32 mantissa halves look like big
// exponents ~40% of the time; bf16 activations never.
// ---------------------------------------------------------------------------
__global__ __launch_bounds__(256) void detect_kernel(
    const unsigned short* __restrict__ x, int* __restrict__ flag) {
  __shared__ int cnt[256];
  const int tid = threadIdx.x;
  int c = 0;
  for (int i = tid; i < 4096; i += 256) {
    const unsigned short u = x[2 * i];
    const int e = (u >> 7) & 0xFF;
    if (e >= 154) ++c;
  }
  cnt[tid] = c;
  __syncthreads();
  for (int s = 128; s > 0; s >>= 1) {
    if (tid < s) cnt[tid] += cnt[tid + s];
    __syncthreads();
  }
  if (tid == 0) *flag = cnt[0];
}

// x -> canonical bf16, 4 elems/thread
__global__ __launch_bounds__(256) void convert_x_kernel(
    const void* __restrict__ src, unsigned short* __restrict__ dst,
    const int* __restrict__ flag, int n4) {
  const int i = blockIdx.x * 256 + threadIdx.x;
  if (i >= n4) return;
  const bool isf = (*flag > 64);
  u16x4 o;
  if (isf) {
    const float4 f = ((const float4*)src)[i];
    o[0] = f2b(f.x); o[1] = f2b(f.y); o[2] = f2b(f.z); o[3] = f2b(f.w);
  } else {
    o = ((const u16x4*)src)[i];
  }
  *(u16x4*)(dst + 4 * (size_t)i) = o;
}

// ---------------------------------------------------------------------------
// 64x64-tile batched transpose, vectorized BOTH sides (G13):
// loads float4(fp32)/u16x4(bf16), stores u16x4 along output rows.
// LDS tile [64][66] (pad-66: 2-way bank conflicts only, free per m136).
// Requires R%64==0, C%64==0 (all our shapes: 2048x128, 2048x2048).
// ---------------------------------------------------------------------------
__global__ __launch_bounds__(256) void transpose64_kernel(
    const void* __restrict__ src, unsigned short* __restrict__ dst,
    int R, int C, const int* __restrict__ flag) {
  __shared__ unsigned short tile[64][66];
  const bool isf = (*flag > 64);
  const int c0 = blockIdx.x * 64, r0 = blockIdx.y * 64;
  const size_t base = (size_t)blockIdx.z * R * C;
  const int tx = threadIdx.x & 15, ty = threadIdx.x >> 4;
#pragma unroll
  for (int j = 0; j < 4; ++j) {
    const int rl = ty + j * 16;
    const size_t idx = base + (size_t)(r0 + rl) * C + c0 + tx * 4;
    u16x4 v;
    if (isf) {
      const float4 f = *(const float4*)((const float*)src + idx);
      v[0] = f2b(f.x); v[1] = f2b(f.y); v[2] = f2b(f.z); v[3] = f2b(f.w);
    } else {
      v = *(const u16x4*)((const unsigned short*)src + idx);
    }
    *(u16x4*)(&tile[rl][tx * 4]) = v;
  }
  __syncthreads();
#pragma unroll
  for (int j = 0; j < 4; ++j) {
    const int cl = ty + j * 16;
    u16x4 v;
#pragma unroll
    for (int k = 0; k < 4; ++k) v[k] = tile[tx * 4 + k][cl];
    *(u16x4*)(dst + base + (size_t)(c0 + cl) * R + r0 + tx * 4) = v;
  }
}

// bf16-only 64x64 batched transpose (V [t][h] -> [h][t] per (b,n))
__global__ __launch_bounds__(256) void transpose64_bf16_kernel(
    const unsigned short* __restrict__ src, unsigned short* __restrict__ dst,
    int R, int C) {
  __shared__ unsigned short tile[64][66];
  const int c0 = blockIdx.x * 64, r0 = blockIdx.y * 64;
  const size_t base = (size_t)blockIdx.z * R * C;
  const int tx = threadIdx.x & 15, ty = threadIdx.x >> 4;
#pragma unroll
  for (int j = 0; j < 4; ++j) {
    const int rl = ty + j * 16;
    *(u16x4*)(&tile[rl][tx * 4]) =
        *(const u16x4*)(src + base + (size_t)(r0 + rl) * C + c0 + tx * 4);
  }
  __syncthreads();
#pragma unroll
  for (int j = 0; j < 4; ++j) {
    const int cl = ty + j * 16;
    u16x4 v;
#pragma unroll
    for (int k = 0; k < 4; ++k) v[k] = tile[tx * 4 + k][cl];
    *(u16x4*)(dst + base + (size_t)(c0 + cl) * R + r0 + tx * 4) = v;
  }
}

// ---------------------------------------------------------------------------
// 256x256-tile bf16 GEMM (QKV projection), K=2048, BK=64, 8 waves (2M x 4N),
// 8-phase schedule, counted vmcnt(4), setprio. R3-exact (124 us, MfmaUtil 35%,
// 0 bank conflicts; R4's drain-removal variant regressed to 143 us — the
// lgkmcnt(0)+sched_barrier after s_barrier is part of the verified template).
// ---------------------------------------------------------------------------
__global__ __launch_bounds__(512, 2) void gemm256_kernel(
    const unsigned short* __restrict__ A,
    const unsigned short* __restrict__ Bt,
    void* __restrict__ outp,
    int mode, const int* __restrict__ flag) {
  constexpr int K = D_;
  __shared__ unsigned short As[2][16384];
  __shared__ unsigned short Bs[2][16384];
  const int tid = threadIdx.x;
  const int lane = tid & 63;
  const int lr = lane & 15, lq = lane >> 4;
  const int wave = tid >> 6;
  const int wm = (wave >> 2) * 128, wn = (wave & 3) * 64;
  const size_t m0 = (size_t)blockIdx.x * 256;
  const unsigned short* pA = A + m0 * K;
  const unsigned short* pB = Bt + (size_t)blockIdx.y * 256 * K;

  // flag read pinned BEFORE prologue staging + drained, so the hand-counted
  // vmcnt(4)s below only ever count our global_load_lds ops.
  const int fv = *flag;
  asm volatile("s_waitcnt vmcnt(0)" ::: "memory");

  // staging geometry: per half-tile, slot16B = j*512+tid (j=0,1);
  // row = j*128+(tid>>2), phys chunk = tid&3, global chunk = phys ^ ((row>>1)&3)
  const int cgs = (tid & 3) ^ ((tid >> 3) & 3);
  const size_t gbase = (size_t)(tid >> 2) * K + (size_t)(cgs * 8);

  // fragment-read bases (ushort offsets): row stride 32, chunk = lq ^ ((row>>1)&3)
  const int swz = (lr >> 1) & 3;
  const int aoff = (wm + lr) * 32 + ((lq ^ swz) << 3);
  const int boff = (wn + lr) * 32 + ((lq ^ swz) << 3);

  f32x4 acc[8][4] = {};
  s16x8 af[8], bf[2];

#define STAGE(mat, ptr, ibuf, kk, h)                                          \
  {                                                                           \
    _Pragma("unroll")                                                         \
    for (int j = 0; j < 2; ++j)                                               \
      __builtin_amdgcn_global_load_lds(                                       \
          (cglobal_void*)((ptr) + gbase + (size_t)j * 128 * K + (kk) + (h) * 32), \
          (lds_void*)(&mat[ibuf][(h) * 8192 + (j * 512 + tid) * 8]), 16, 0, 0); \
  }

#define LOAD_A(kq)                                                            \
  {                                                                           \
    _Pragma("unroll")                                                         \
    for (int mb = 0; mb < 8; ++mb)                                            \
      af[mb] = *(const s16x8*)(&As[ib][(kq) * 8192 + aoff + mb * 512]);       \
  }

#define LOAD_B(kq, nh)                                                        \
  {                                                                           \
    _Pragma("unroll")                                                         \
    for (int nb = 0; nb < 2; ++nb)                                            \
      bf[nb] = *(const s16x8*)(&Bs[ib][(kq) * 8192 + boff + ((nh) * 2 + nb) * 512]); \
  }

#define PHASE_MID()                                                           \
  __builtin_amdgcn_s_barrier();                                               \
  asm volatile("s_waitcnt lgkmcnt(0)" ::: "memory");                          \
  __builtin_amdgcn_sched_barrier(0);

#define MFMA16(nh)                                                            \
  __builtin_amdgcn_s_setprio(1);                                              \
  {                                                                           \
    _Pragma("unroll")                                                         \
    for (int mb = 0; mb < 8; ++mb) {                                          \
      acc[mb][(nh) * 2] = __builtin_amdgcn_mfma_f32_16x16x32_bf16(            \
          af[mb], bf[0], acc[mb][(nh) * 2], 0, 0, 0);                         \
      acc[mb][(nh) * 2 + 1] = __builtin_amdgcn_mfma_f32_16x16x32_bf16(        \
          af[mb], bf[1], acc[mb][(nh) * 2 + 1], 0, 0, 0);                     \
    }                                                                         \
  }                                                                           \
  __builtin_amdgcn_s_setprio(0);

#define PHASE_END() __builtin_amdgcn_s_barrier();
#define VM4() asm volatile("s_waitcnt vmcnt(4)" ::: "memory");

  // prologue: stage K-tile 0 into buf 0 (order: A0, B0, A1, B1)
  STAGE(As, pA, 0, 0, 0);
  STAGE(Bs, pB, 0, 0, 0);
  STAGE(As, pA, 0, 0, 1);
  STAGE(Bs, pB, 0, 0, 1);
  VM4();  // A0,B0 landed; A1,B1 (4 loads) stay in flight
  __builtin_amdgcn_s_barrier();

  for (int t = 0; t < K / 64; ++t) {
    const int ib = t & 1;
    const int kn = (t + 1) * 64;  // next K-tile (t=31 reads mapped scratch)
    // phase 0: kslice 0, nb 0-1
    LOAD_A(0); LOAD_B(0, 0);
    STAGE(As, pA, ib ^ 1, kn, 0);
    PHASE_MID(); MFMA16(0); PHASE_END();
    // phase 1: kslice 0, nb 2-3
    LOAD_B(0, 1);
    STAGE(Bs, pB, ib ^ 1, kn, 0);
    VM4();  // lands A-h1,B-h1 of K-tile t (read in phase 2)
    PHASE_MID(); MFMA16(1); PHASE_END();
    // phase 2: kslice 1, nb 0-1
    LOAD_A(1); LOAD_B(1, 0);
    STAGE(As, pA, ib ^ 1, kn, 1);
    PHASE_MID(); MFMA16(0); PHASE_END();
    // phase 3: kslice 1, nb 2-3
    LOAD_B(1, 1);
    STAGE(Bs, pB, ib ^ 1, kn, 1);
    VM4();  // lands A-h0,B-h0 of K-tile t+1 (read in next phase 0)
    PHASE_MID(); MFMA16(1); PHASE_END();
  }

  const int n0 = blockIdx.y << 8;
  if (mode == 0) {
    const bool isf = (fv > 64);
#pragma unroll
    for (int mb = 0; mb < 8; ++mb) {
#pragma unroll
      for (int i = 0; i < 4; ++i) {
        const size_t r = m0 + wm + mb * 16 + lq * 4 + i;
#pragma unroll
        for (int nb = 0; nb < 4; ++nb) {
          const size_t c = (size_t)(n0 + wn + nb * 16 + lr);
          if (isf) ((float*)outp)[r * D_ + c] = acc[mb][nb][i];
          else ((unsigned short*)outp)[r * D_ + c] = f2b(acc[mb][nb][i]);
        }
      }
    }
  } else {
    unsigned short* op = (unsigned short*)outp;
    const size_t SB = (size_t)B_ * N_ * T_ * H_;
#pragma unroll
    for (int mb = 0; mb < 8; ++mb) {
#pragma unroll
      for (int i = 0; i < 4; ++i) {
        const size_t r = m0 + wm + mb * 16 + lq * 4 + i;
        const int b = (int)(r >> 11);
        const int tt = (int)(r & 2047);
#pragma unroll
        for (int nb = 0; nb < 4; ++nb) {
          const int g = n0 + wn + nb * 16 + lr;
          const int s = g >> 11, n = (g >> 7) & 15, h = g & 127;
          op[(size_t)s * SB + (size_t)(b * N_ + n) * T_ * H_ +
             (size_t)tt * H_ + h] = f2b(acc[mb][nb][i]);
        }
      }
    }
  }
#undef STAGE
#undef LOAD_A
#undef LOAD_B
#undef PHASE_MID
#undef MFMA16
#undef PHASE_END
#undef VM4
}

// ---------------------------------------------------------------------------
// 256x128-tile bf16 GEMM (out-projection): 256 blocks, 1 block/CU, 1 round.
// Triple-buffered LDS, counted vmcnt(6), setprio, XCD swizzle. R3-exact.
// ---------------------------------------------------------------------------
__global__ __launch_bounds__(512, 2) void gemm256x128_kernel(
    const unsigned short* __restrict__ A,
    const unsigned short* __restrict__ Bt,
    void* __restrict__ outp,
    int mode, const int* __restrict__ flag) {
  constexpr int K = D_;
  __shared__ unsigned short As[3 * 16384];
  __shared__ unsigned short Bs[3 * 8192];
  const int tid = threadIdx.x;
  const int lane = tid & 63;
  const int lr = lane & 15, lq = lane >> 4;
  const int wave = tid >> 6;
  const int wm = (wave >> 1) * 64, wn = (wave & 1) * 64;

  // T1: bijective XCD-chunked swizzle (gridDim.x == 16).
  const int lin = blockIdx.y * 16 + blockIdx.x;
  const int nblk = (int)(gridDim.x * gridDim.y);  // 256, %8==0
  const int wg = (lin & 7) * (nblk >> 3) + (lin >> 3);
  const int bx = wg & 15;
  const int by = wg >> 4;

  const size_t m0 = (size_t)bx * 256;
  const unsigned short* pA = A + m0 * K;
  const unsigned short* pB = Bt + (size_t)by * 128 * K;

  const int fv = *flag;
  asm volatile("s_waitcnt vmcnt(0)" ::: "memory");

  const int cgs = (tid & 3) ^ ((tid >> 3) & 3);
  const size_t gbase = (size_t)(tid >> 2) * K + (size_t)(cgs * 8);

  const int swz = (lr >> 1) & 3;
  const int aoff = (wm + lr) * 32 + ((lq ^ swz) << 3);
  const int boff = (wn + lr) * 32 + ((lq ^ swz) << 3);

  f32x4 acc[4][4] = {};
  s16x8 af[4], bf[4];

#define STAGE_A(bufp, kk, h)                                                  \
  {                                                                           \
    _Pragma("unroll")                                                         \
    for (int j = 0; j < 2; ++j)                                               \
      __builtin_amdgcn_global_load_lds(                                       \
          (cglobal_void*)(pA + gbase + (size_t)j * 128 * K + (kk) + (h) * 32),\
          (lds_void*)((bufp) + (h) * 8192 + (j * 512 + tid) * 8), 16, 0, 0);  \
  }
#define STAGE_B(bufp, kk, h)                                                  \
  __builtin_amdgcn_global_load_lds(                                           \
      (cglobal_void*)(pB + gbase + (kk) + (h) * 32),                          \
      (lds_void*)((bufp) + (h) * 4096 + tid * 8), 16, 0, 0);

#define LOAD_F(h)                                                             \
  {                                                                           \
    _Pragma("unroll")                                                         \
    for (int i = 0; i < 4; ++i) {                                             \
      af[i] = *(const s16x8*)(Ab + (h) * 8192 + aoff + i * 512);              \
      bf[i] = *(const s16x8*)(Bb + (h) * 4096 + boff + i * 512);              \
    }                                                                         \
  }

#define PHASE_MID()                                                           \
  __builtin_amdgcn_s_barrier();                                               \
  asm volatile("s_waitcnt lgkmcnt(0)" ::: "memory");                          \
  __builtin_amdgcn_sched_barrier(0);

#define MFMA16()                                                              \
  __builtin_amdgcn_s_setprio(1);                                              \
  {                                                                           \
    _Pragma("unroll")                                                         \
    for (int mb = 0; mb < 4; ++mb) {                                          \
      _Pragma("unroll")                                                       \
      for (int nb = 0; nb < 4; ++nb)                                          \
        acc[mb][nb] = __builtin_amdgcn_mfma_f32_16x16x32_bf16(                \
            af[mb], bf[nb], acc[mb][nb], 0, 0, 0);                            \
    }                                                                         \
  }                                                                           \
  __builtin_amdgcn_s_setprio(0);

#define PHASE_END() __builtin_amdgcn_s_barrier();
#define VM6() asm volatile("s_waitcnt vmcnt(6)" ::: "memory");

  STAGE_A(As, 0, 0); STAGE_A(As, 0, 1); STAGE_B(Bs, 0, 0); STAGE_B(Bs, 0, 1);
  STAGE_A(As + 16384, 64, 0); STAGE_A(As + 16384, 64, 1);
  STAGE_B(Bs + 8192, 64, 0);  STAGE_B(Bs + 8192, 64, 1);
  VM6();
  __builtin_amdgcn_s_barrier();

  int bt = 0, bp = 2;
  for (int t = 0; t < K / 64; ++t) {
    const unsigned short* Ab = As + bt * 16384;
    const unsigned short* Bb = Bs + bt * 8192;
    unsigned short* Ap = As + bp * 16384;
    unsigned short* Bp = Bs + bp * 8192;
    const int kn = (t + 2) * 64;  // prefetch K-tile t+2 (tail spills <1KB)
    LOAD_F(0);
    STAGE_A(Ap, kn, 0); STAGE_B(Bp, kn, 0);
    PHASE_MID(); MFMA16(); PHASE_END();
    LOAD_F(1);
    STAGE_A(Ap, kn, 1); STAGE_B(Bp, kn, 1);
    VM6();
    PHASE_MID(); MFMA16(); PHASE_END();
    bt = (bt == 2) ? 0 : bt + 1;
    bp = (bp == 2) ? 0 : bp + 1;
  }

  const int n0 = by << 7;
  if (mode == 0) {
    const bool isf = (fv > 64);
#pragma unroll
    for (int mb = 0; mb < 4; ++mb) {
#pragma unroll
      for (int i = 0; i < 4; ++i) {
        const size_t r = m0 + wm + mb * 16 + lq * 4 + i;
#pragma unroll
        for (int nb = 0; nb < 4; ++nb) {
          const size_t c = (size_t)(n0 + wn + nb * 16 + lr);
          if (isf) ((float*)outp)[r * D_ + c] = acc[mb][nb][i];
          else ((unsigned short*)outp)[r * D_ + c] = f2b(acc[mb][nb][i]);
        }
      }
    }
  } else {
    unsigned short* op = (unsigned short*)outp;
    const size_t SB = (size_t)B_ * N_ * T_ * H_;
#pragma unroll
    for (int mb = 0; mb < 4; ++mb) {
#pragma unroll
      for (int i = 0; i < 4; ++i) {
        const size_t r = m0 + wm + mb * 16 + lq * 4 + i;
        const int b = (int)(r >> 11);
        const int tt = (int)(r & 2047);
#pragma unroll
        for (int nb = 0; nb < 4; ++nb) {
          const int g = n0 + wn + nb * 16 + lr;
          const int s = g >> 11, n = (g >> 7) & 15, h = g & 127;
          op[(size_t)s * SB + (size_t)(b * N_ + n) * T_ * H_ +
             (size_t)tt * H_ + h] = f2b(acc[mb][nb][i]);
        }
      }
    }
  }
#undef STAGE_A
#undef STAGE_B
#undef LOAD_F
#undef PHASE_MID
#undef MFMA16
#undef PHASE_END
#undef VM6
}

// ---------------------------------------------------------------------------
// RoPE in place on q,k rows — vectorized (G13): 16 lanes/row, u16x4 pairs
// (8B loads/stores), 4 rows/wave, 16 rows/block. Same sincos count as scalar
// version, 4x fewer memory instructions. q scaled by H^-0.5.
// ---------------------------------------------------------------------------
__global__ __launch_bounds__(256) void rope_kernel(unsigned short* __restrict__ qk) {
  const int tid = threadIdx.x;
  const int lane = tid & 63;
  const int lr = lane & 15;           // 16 lanes per row, 4 elems each
  const size_t row = (size_t)blockIdx.x * 16 + (tid >> 4);
  const int t = (int)(row & (T_ - 1));
  const int s = (int)(row >> 16);     // 0 = q, 1 = k
  unsigned short* p = qk + row * H_ + lr * 4;
  u16x4 v1 = *(const u16x4*)(p);
  u16x4 v2 = *(const u16x4*)(p + 64);
  u16x4 o1, o2;
  const float qs = (s == 0) ? 0.08838834764831845f : 1.0f;
#pragma unroll
  for (int k = 0; k < 4; ++k) {
    const int h = lr * 4 + k;
    // timescale^-1 = 10000^(-h/64) = exp2(-h*log2(10000)/64)
    const float inv_ts = exp2f(-0.20762050f * (float)h);
    float sv, cv;
    __sincosf((float)t * inv_ts, &sv, &cv);
    const float x1 = b2f(v1[k]), x2 = b2f(v2[k]);
    o1[k] = f2b((x1 * cv - x2 * sv) * qs);
    o2[k] = f2b((x2 * cv + x1 * sv) * qs);
  }
  *(u16x4*)(p) = o1;
  *(u16x4*)(p + 64) = o2;
}

// ---------------------------------------------------------------------------
// Flash attention, double-buffered K/V prefetch (T3/T4/T14 applied).
//   Ks[2][64 key][128 h] : phys chunk16 = logical ^ (key&15)
//   Vt[2][128 h][64 key] : phys chunk8  = logical ^ (h&7)
//   Psm[wave][16x64]     : per-wave PRIVATE -> P write/read needs no barrier
// Per iter: issue 8 global_load_lds for tile i+1 (unconditional; tail strays
// <=16KB into allocated ws so vmcnt counts stay uniform), s_waitcnt vmcnt(8)
// (tile i complete, tile i+1 in flight), raw s_barrier, QK^T, softmax, P
// (wave-local), PV, raw s_barrier. LDS 72KB -> 2 blocks/CU.
// p = exp2(-2*C_T*rcp(u+1) + BIAS), u = exp2(a*C_IN): same softmax weights
// (constant absorbed by l).
// ---------------------------------------------------------------------------
__global__ __launch_bounds__(256, 2) void attn_kernel(
    const unsigned short* __restrict__ qkv,
    const unsigned short* __restrict__ vt,
    unsigned short* __restrict__ enc) {
  const int tid = threadIdx.x, lane = tid & 63, wave = tid >> 6;
  const int lr = lane & 15, lq = lane >> 4;
  const int bn = blockIdx.x;
  const int b = bn >> 4, n = bn & 15;
  const int t0 = blockIdx.y * 64;
  const size_t SB = (size_t)B_ * N_ * T_ * H_;
  const unsigned short* qp = qkv + (size_t)bn * T_ * H_;
  const unsigned short* kp = qp + SB;
  const unsigned short* vp = vt + (size_t)bn * T_ * H_;  // [h][t]

  __shared__ unsigned short Ks[2][64 * 128];
  __shared__ unsigned short Vt[2][128 * 64];
  __shared__ unsigned short Psm[4][16 * 64];
  unsigned short* Ps = Psm[wave];  // per-wave private: no barrier needed

  // staging offsets (lane-invariant across j except row):
  const int cgK = (tid & 15) ^ ((tid >> 4) & 15);   // 16 chunks/row
  const int cgV = (tid & 7) ^ ((tid >> 3) & 7);     // 8 chunks/row
  size_t goffK[4], goffV[4];
#pragma unroll
  for (int j = 0; j < 4; ++j) {
    goffK[j] = (size_t)(j * 16 + (tid >> 4)) * H_ + cgK * 8;
    goffV[j] = (size_t)(j * 32 + (tid >> 3)) * T_ + cgV * 8;
  }

  // Q fragments (A-layout), registers for whole kernel
  s16x8 aq[4];
  {
    const int t = t0 + wave * 16 + lr;
#pragma unroll
    for (int kc = 0; kc < 4; ++kc)
      aq[kc] = *(const s16x8*)(qp + (size_t)t * H_ + kc * 32 + lq * 8);
  }
  // drain Q loads so the hand-counted vmcnt(8) below only counts staging
  asm volatile("s_waitcnt vmcnt(0)" ::: "memory");

#define STAGE_T(ibuf, s0v)                                                    \
  {                                                                           \
    _Pragma("unroll")                                                         \
    for (int j = 0; j < 4; ++j) {                                             \
      __builtin_amdgcn_global_load_lds(                                       \
          (cglobal_void*)(kp + (size_t)(s0v) * H_ + goffK[j]),                \
          (lds_void*)(Ks[ibuf] + (size_t)(j * 256 + tid) * 8), 16, 0, 0);     \
      __builtin_amdgcn_global_load_lds(                                       \
          (cglobal_void*)(vp + goffV[j] + (s0v)),                             \
          (lds_void*)(Vt[ibuf] + (size_t)(j * 256 + tid) * 8), 16, 0, 0);     \
    }                                                                         \
  }

  f32x4 oacc[8] = {};
  float lp[4] = {0.f, 0.f, 0.f, 0.f};

  const int s_lo = (t0 >= WIN - 1) ? ((t0 - (WIN - 1)) & ~63) : 0;
  constexpr float C_IN = 0.05770780f;     // 2*log2(e)/50
  constexpr float M_SCALE = -144.269504f; // -2*50*log2(e)
  constexpr float M_BIAS = 86.56f;        // keeps p in [2^-58, 2^87]

  // prologue: tile s_lo -> buf 0 (8 loads in flight)
  STAGE_T(0, s_lo);

  int cur = 0;
  for (int s0 = s_lo; s0 <= t0 + 63; s0 += 64) {
    // prefetch next tile into the other buffer (safe: all waves passed the
    // previous iteration's end barrier, so reads of that buffer are done;
    // tail iteration strays into adjacent allocated workspace, values unused)
    STAGE_T(cur ^ 1, s0 + 64);
    asm volatile("s_waitcnt vmcnt(8)" ::: "memory");  // tile s0 landed
    __builtin_amdgcn_s_barrier();                     // visible to all waves

    const unsigned short* Kb = Ks[cur];
    const unsigned short* Vb = Vt[cur];

    // QK^T -> p
    float p[4][4];
#pragma unroll
    for (int sb = 0; sb < 4; ++sb) {
      f32x4 a = {};
#pragma unroll
      for (int kc = 0; kc < 4; ++kc) {
        const int co = (((kc << 2) + lq) ^ lr) * 8;
        s16x8 bk = *(const s16x8*)(Kb + (sb * 16 + lr) * 128 + co);
        a = __builtin_amdgcn_mfma_f32_16x16x32_bf16(aq[kc], bk, a, 0, 0, 0);
      }
#pragma unroll
      for (int i = 0; i < 4; ++i) {
        const float u = exp2f(a[i] * C_IN);
        const float r = __builtin_amdgcn_rcpf(u + 1.0f);
        p[sb][i] = exp2f(fmaf(r, M_SCALE, M_BIAS));
      }
    }

    // mask only boundary tiles (wave-uniform branch)
    const bool interior = (s0 + 63 <= t0) && (s0 >= t0 + 63 - (WIN - 1));
    if (!interior) {
#pragma unroll
      for (int sb = 0; sb < 4; ++sb) {
        const int key = s0 + sb * 16 + lr;
#pragma unroll
        for (int i = 0; i < 4; ++i) {
          const int t = t0 + wave * 16 + lq * 4 + i;
          if (key > t || key < t - (WIN - 1)) p[sb][i] = 0.0f;
        }
      }
    }
#pragma unroll
    for (int sb = 0; sb < 4; ++sb)
#pragma unroll
      for (int i = 0; i < 4; ++i) lp[i] += p[sb][i];

    // P -> per-wave private LDS (no barrier: same-wave write->read, lgkmcnt)
#pragma unroll
    for (int sb = 0; sb < 4; ++sb)
#pragma unroll
      for (int i = 0; i < 4; ++i) {
        const int row = lq * 4 + i;
        const int cph = ((sb * 2 + (lr >> 3)) ^ (row & 7));
        Ps[row * 64 + cph * 8 + (lr & 7)] = f2b(p[sb][i]);
      }

    s16x8 ap[2];
#pragma unroll
    for (int kc = 0; kc < 2; ++kc)
      ap[kc] = *(const s16x8*)(Ps + lr * 64 + ((((kc << 2) + lq) ^ (lr & 7)) * 8));

#pragma unroll
    for (int hb = 0; hb < 8; ++hb) {
#pragma unroll
      for (int kc = 0; kc < 2; ++kc) {
        const int co = (((kc << 2) + lq) ^ (lr & 7)) * 8;
        s16x8 bv = *(const s16x8*)(Vb + (hb * 16 + lr) * 64 + co);
        oacc[hb] = __builtin_amdgcn_mfma_f32_16x16x32_bf16(ap[kc], bv, oacc[hb], 0, 0, 0);
      }
    }

    __builtin_amdgcn_s_barrier();  // all reads of buf cur complete
    cur ^= 1;
  }
#undef STAGE_T

  // l: reduce per-lane partials across the 16 lr-lanes
#pragma unroll
  for (int i = 0; i < 4; ++i) {
#pragma unroll
    for (int off = 1; off < 16; off <<= 1)
      lp[i] += __shfl_xor(lp[i], off, 64);
  }

#pragma unroll
  for (int i = 0; i < 4; ++i) {
    const int t = t0 + wave * 16 + lq * 4 + i;
    const float inv = 1.0f / lp[i];
    const size_t rowb = ((size_t)b * T_ + t) * (N_ * H_) + (size_t)n * H_;
#pragma unroll
    for (int hb = 0; hb < 8; ++hb)
      enc[rowb + hb * 16 + lr] = f2b(oacc[hb][i] * inv);
  }
}

// ---------------------------------------------------------------------------
extern "C" void kernel_launch(void* const* d_in, const int* in_sizes, int n_in,
                              void* d_out, int out_size, void* d_ws, size_t ws_size,
                              hipStream_t stream) {
  const void* x     = d_in[0];  // (B,T,D)    fp32 (auto-detected; bf16 hedge)
  const void* w_qkv = d_in[1];  // (3,N,D,H)
  const void* w_out = d_in[2];  // (N,H,D)

  // workspace (88 MB peak, proven safe):
  //   [0,64)          flag
  //   A [64,+16MB)    xc        -> later vt (v transposed, 16MB)
  //   B [+16,+40MB)   wqkvT     -> later enc(16MB) + woutT(8MB)
  //   C [+40,+88MB)   qkv: q(16) k(16) v(16)
  char* wsb = (char*)d_ws;
  int* flag = (int*)wsb;
  const size_t MB = 1048576;
  unsigned short* xc    = (unsigned short*)(wsb + 64);
  unsigned short* wqkvT = (unsigned short*)(wsb + 64 + 16 * MB);
  unsigned short* qkv   = (unsigned short*)(wsb + 64 + 40 * MB);
  unsigned short* vt    = xc;                                        // alias
  unsigned short* enc   = wqkvT;                                     // alias
  unsigned short* woutT = (unsigned short*)(wsb + 64 + 32 * MB);     // alias
  unsigned short* v     = qkv + 2 * (size_t)B_ * N_ * T_ * H_;

  detect_kernel<<<1, 256, 0, stream>>>((const unsigned short*)x, flag);
  convert_x_kernel<<<8192, 256, 0, stream>>>(x, xc, flag, B_ * T_ * D_ / 4);
  transpose64_kernel<<<dim3(2, 32, 48), 256, 0, stream>>>(w_qkv, wqkvT, 2048, 128, flag);
  gemm256_kernel<<<dim3(16, 24), 512, 0, stream>>>(xc, wqkvT, qkv, 1, flag);
  rope_kernel<<<8192, 256, 0, stream>>>(qkv);
  transpose64_bf16_kernel<<<dim3(2, 32, 32), 256, 0, stream>>>(v, vt, 2048, 128);
  transpose64_kernel<<<dim3(32, 32, 1), 256, 0, stream>>>(w_out, woutT, 2048, 2048, flag);
  attn_kernel<<<dim3(32, 32), 256, 0, stream>>>(qkv, vt, enc);
  gemm256x128_kernel<<<dim3(16, 16), 512, 0, stream>>>(enc, woutT, d_out, 0, flag);
}